// Round 3
// baseline (230.297 us; speedup 1.0000x reference)
//
#include <hip/hip_runtime.h>
#include <hip/hip_bf16.h>

#define TAPS 901
#define CB 256
#define R 4
#define OPB (CB * R)            // 1024 outputs per block
#define MAXNK 1808              // worst-case padded combined-kernel taps (mult of 8)
#define TILE (OPB + MAXNK + 40) // window floats staged per block

__device__ __forceinline__ float4 ld4(const float* p) {
  return *reinterpret_cast<const float4*>(p);
}

// ---------------------------------------------------------------------------
// Kernel 1: build rot/gauss kernels, the combined kernel comb = conv(rot,gauss),
// and all bounds. bounds = {clo4, nk8, flo, fhi, rlo, rhi, glo, ghi}
//   comb conv form: c[i] = sum_t comb[t] * f[i + t - 900], t in [clo4, clo4+nk8)
//   flo/fhi: pixel counts at the lo/hi edge where combined != exact two-pass.
// ---------------------------------------------------------------------------
__global__ __launch_bounds__(1024) void build_all(
    const float* __restrict__ lns, const float* __restrict__ lnv,
    float* __restrict__ rot_w, float* __restrict__ gauss_w,
    float* __restrict__ comb_w, int* __restrict__ bounds) {
  __shared__ float rk[1024], gk[1024], red[1024];
  __shared__ int sb[8];  // {rlo,rhi,glo,ghi,clo,chi,-,-}
  const int t = threadIdx.x;
  if (t < 8) sb[t] = (t & 1) ? -1 : 4096;
  __syncthreads();

  const float sigma = 0.01f + expf(lns[0]);
  const float vsini = 0.9f + expf(lnv[0]);

  float rv = 0.f, gv = 0.f;
  if (t < TAPS) {
    float g = -4.5f + 0.01f * (float)t;
    float x = (299792.458f * g / 10500.0f) / vsini;
    float x2 = fminf(x * x, 1.0f);
    if (x2 < 1.0f) rv = 2.0f * sqrtf(1.0f - x2);  // 0.99999999f rounds to 1.0f
    gv = (1.0f / (sigma * sqrtf(2.0f * 3.1415926654f))) *
         expf(-0.5f * g * g / (sigma * sigma)) * 0.01f;
  }
  red[t] = rv;
  __syncthreads();
  for (int s = 512; s > 0; s >>= 1) {
    if (t < s) red[t] += red[t + s];
    __syncthreads();
  }
  const float rsum = red[0];

  const float rw = (t < TAPS) ? rv / rsum : 0.f;
  rk[t] = rw;
  gk[t] = gv;
  rot_w[t] = rw;
  gauss_w[t] = gv;
  if (t < TAPS) {
    if (rw != 0.f)          { atomicMin(&sb[0], t); atomicMax(&sb[1], t); }
    if (fabsf(gv) > 1e-10f) { atomicMin(&sb[2], t); atomicMax(&sb[3], t); }
  }
  __syncthreads();
  const int rlo = sb[0], rhi = sb[1], glo = sb[2], ghi = sb[3];

  // combined kernel comb[t] = sum_j rot[j]*gauss[t-j]  (t in [0,1800])
  for (int t2 = t; t2 < 2048; t2 += 1024) {
    float c = 0.f;
    if (t2 <= 1800) {
      int jmin = rlo > t2 - ghi ? rlo : t2 - ghi;
      int jmax = rhi < t2 - glo ? rhi : t2 - glo;
      for (int j = jmin; j <= jmax; ++j) c += rk[j] * gk[t2 - j];
    }
    comb_w[t2] = c;
    if (t2 <= 1800 && fabsf(c) > 1e-12f) { atomicMin(&sb[4], t2); atomicMax(&sb[5], t2); }
  }
  __syncthreads();
  if (t == 0) {
    int clo = sb[4], chi = sb[5];
    if (chi < clo) { clo = 900; chi = 900; }
    int clo4 = clo & ~3;
    int nk8 = ((chi - clo4 + 1) + 7) & ~7;
    if (nk8 > MAXNK) nk8 = MAXNK;
    int flo = 450 - glo; if (flo < 0) flo = 0;
    int fhi = ghi - 450; if (fhi < 0) fhi = 0;
    bounds[0] = clo4; bounds[1] = nk8; bounds[2] = flo; bounds[3] = fhi;
    bounds[4] = rlo;  bounds[5] = rhi; bounds[6] = glo; bounds[7] = ghi;
  }
}

// ---------------------------------------------------------------------------
// Kernel 2: exact two-stage conv for the edge pixels the combined form gets
// wrong (i < flo, i >= n-fhi), scattered into sums. 2 blocks (lo/hi edge).
// ---------------------------------------------------------------------------
__global__ __launch_bounds__(256) void edge_fix(
    const float* __restrict__ flux, const float* __restrict__ rot_w,
    const float* __restrict__ gauss_w, const int* __restrict__ bounds,
    const int* __restrict__ ids, float* __restrict__ sums, int n) {
  __shared__ float rbuf[928];
  const int tid = threadIdx.x;
  const int flo = bounds[2], fhi = bounds[3];
  const int rlo = bounds[4], rhi = bounds[5], glo = bounds[6], ghi = bounds[7];
  const int m = flo + fhi;  // r-values needed per edge (<= 901)

  if (blockIdx.x == 0) {
    // lo edge: pixels i in [0, flo); r[j] for j in [0, m)
    for (int j = tid; j < m; j += 256) {
      float s = 0.f;
      int j0 = 450 - j > rlo ? 450 - j : rlo;  // f index >= 0
      for (int j2 = j0; j2 <= rhi; ++j2) s += rot_w[j2] * flux[j + j2 - 450];
      rbuf[j] = s;
    }
    __syncthreads();
    for (int i = tid; i < flo; i += 256) {
      float c = 0.f;
      int k0 = 450 - i > glo ? 450 - i : glo;  // r index >= 0
      for (int k = k0; k <= ghi; ++k) c += gauss_w[k] * rbuf[i + k - 450];
      atomicAdd(&sums[ids[i]], c);
    }
  } else {
    // hi edge: pixels i in [n-fhi, n); r[j] for j in [n-m, n)
    const int jbase = n - m;
    for (int jj = tid; jj < m; jj += 256) {
      int j = jbase + jj;
      float s = 0.f;
      int j2hi = n - 1 + 450 - j < rhi ? n - 1 + 450 - j : rhi;  // f index < n
      for (int j2 = rlo; j2 <= j2hi; ++j2) s += rot_w[j2] * flux[j + j2 - 450];
      rbuf[jj] = s;
    }
    __syncthreads();
    for (int ii = tid; ii < fhi; ii += 256) {
      int i = n - fhi + ii;
      float c = 0.f;
      int khi = n - 1 + 450 - i < ghi ? n - 1 + 450 - i : ghi;  // r index < n
      for (int k = glo; k <= khi; ++k) c += gauss_w[k] * rbuf[i + k - 450 - jbase];
      atomicAdd(&sums[ids[i]], c);
    }
  }
}

// ---------------------------------------------------------------------------
// Kernel 3: fused combined-conv + segment-sum scatter.
// Window ring in 2x float4 regs refilled via ds_read_b128 (16B/lane stride,
// conflict-free); weights broadcast from LDS as float4.
// ---------------------------------------------------------------------------
__global__ __launch_bounds__(CB) void conv_scatter(
    const float* __restrict__ flux, const float* __restrict__ comb_w,
    const int* __restrict__ bounds, const int* __restrict__ ids,
    float* __restrict__ sums, int n) {
  __shared__ __align__(16) float lds[TILE];
  __shared__ __align__(16) float wl[MAXNK];
  const int tid = threadIdx.x;
  const int clo4 = __builtin_amdgcn_readfirstlane(bounds[0]);
  const int nk8  = __builtin_amdgcn_readfirstlane(bounds[1]);
  const int flo  = __builtin_amdgcn_readfirstlane(bounds[2]);
  const int fhi  = __builtin_amdgcn_readfirstlane(bounds[3]);
  const int blockBase = blockIdx.x * OPB;
  const int start = blockBase - 900 + clo4;  // multiple of 4 -> float4-aligned
  const int jend = OPB + nk8 + 8;

  for (int j = tid * 4; j < jend; j += CB * 4) {
    int g = start + j;
    float4 v;
    if (g >= 0 && g + 3 < n) {
      v = ld4(flux + g);
    } else {
      v.x = (unsigned)g       < (unsigned)n ? flux[g]     : 0.f;
      v.y = (unsigned)(g + 1) < (unsigned)n ? flux[g + 1] : 0.f;
      v.z = (unsigned)(g + 2) < (unsigned)n ? flux[g + 2] : 0.f;
      v.w = (unsigned)(g + 3) < (unsigned)n ? flux[g + 3] : 0.f;
    }
    *reinterpret_cast<float4*>(&lds[j]) = v;
  }
  for (int k = tid; k < nk8; k += CB) wl[k] = comb_w[clo4 + k];
  __syncthreads();

  const int idx0 = tid * 4;
  float4 A = ld4(&lds[idx0]);
  float4 B = ld4(&lds[idx0 + 4]);
  float a0 = 0.f, a1 = 0.f, a2 = 0.f, a3 = 0.f;
  for (int kk = 0; kk < nk8; kk += 8) {
    const float4 wA = *reinterpret_cast<const float4*>(&wl[kk]);
    const float4 wB = *reinterpret_cast<const float4*>(&wl[kk + 4]);
    // taps kk..kk+3: window = A[0..3], B[0..2]
    a0 = fmaf(wA.x, A.x, a0); a1 = fmaf(wA.x, A.y, a1); a2 = fmaf(wA.x, A.z, a2); a3 = fmaf(wA.x, A.w, a3);
    a0 = fmaf(wA.y, A.y, a0); a1 = fmaf(wA.y, A.z, a1); a2 = fmaf(wA.y, A.w, a2); a3 = fmaf(wA.y, B.x, a3);
    a0 = fmaf(wA.z, A.z, a0); a1 = fmaf(wA.z, A.w, a1); a2 = fmaf(wA.z, B.x, a2); a3 = fmaf(wA.z, B.y, a3);
    a0 = fmaf(wA.w, A.w, a0); a1 = fmaf(wA.w, B.x, a1); a2 = fmaf(wA.w, B.y, a2); a3 = fmaf(wA.w, B.z, a3);
    A = ld4(&lds[idx0 + kk + 8]);  // refill: window now B[0..3], A'[0..2]
    // taps kk+4..kk+7
    a0 = fmaf(wB.x, B.x, a0); a1 = fmaf(wB.x, B.y, a1); a2 = fmaf(wB.x, B.z, a2); a3 = fmaf(wB.x, B.w, a3);
    a0 = fmaf(wB.y, B.y, a0); a1 = fmaf(wB.y, B.z, a1); a2 = fmaf(wB.y, B.w, a2); a3 = fmaf(wB.y, A.x, a3);
    a0 = fmaf(wB.z, B.z, a0); a1 = fmaf(wB.z, B.w, a1); a2 = fmaf(wB.z, A.x, a2); a3 = fmaf(wB.z, A.y, a3);
    a0 = fmaf(wB.w, B.w, a0); a1 = fmaf(wB.w, A.x, a1); a2 = fmaf(wB.w, A.y, a2); a3 = fmaf(wB.w, A.z, a3);
    B = ld4(&lds[idx0 + kk + 12]);
  }

  // run-merged scatter (sorted ids); skip edge pixels handled by edge_fix
  const int base = blockBase + idx0;
  const int loskip = flo - base;        // r < loskip invalid
  const int hicap = (n - fhi) - base;   // r >= hicap invalid
  int idv[4];
  if (base + 3 < n) {
    int4 iv = *reinterpret_cast<const int4*>(ids + base);
    idv[0] = iv.x; idv[1] = iv.y; idv[2] = iv.z; idv[3] = iv.w;
  } else {
#pragma unroll
    for (int r = 0; r < 4; ++r) idv[r] = (base + r < n) ? ids[base + r] : -1;
  }
  const float acc[4] = {a0, a1, a2, a3};
  int cur = -1; float run = 0.f;
#pragma unroll
  for (int r = 0; r < 4; ++r) {
    if (r >= loskip && r < hicap) {
      if (idv[r] == cur) {
        run += acc[r];
      } else {
        if (cur >= 0) atomicAdd(&sums[cur], run);
        cur = idv[r]; run = acc[r];
      }
    }
  }
  if (cur >= 0) atomicAdd(&sums[cur], run);
}

// ---------------------------------------------------------------------------
// Kernel 4: per-bin mean. One lower_bound per thread + shfl from neighbor
// for the bin end (halves the dependent-load chain vs two searches).
// ---------------------------------------------------------------------------
__global__ __launch_bounds__(256) void seg_mean(
    const float* __restrict__ sums, const int* __restrict__ ids, int n,
    float* __restrict__ out, int out_n) {
  const int gid = blockIdx.x * blockDim.x + threadIdx.x;
  const int b = (gid < out_n) ? gid + 1 : out_n;
  int lo = 0, hi = n;
  while (lo < hi) {
    int mid = (lo + hi) >> 1;
    int v = ids[mid];
    if (v < b) lo = mid + 1; else hi = mid;
  }
  const int s = lo;
  int s2 = __shfl_down(s, 1);
  const int lane = threadIdx.x & 63;
  if (lane == 63 || gid >= out_n - 1) {
    lo = s; hi = n;
    while (lo < hi) {
      int mid = (lo + hi) >> 1;
      int v = ids[mid];
      if (v < b + 1) lo = mid + 1; else hi = mid;
    }
    s2 = lo;
  }
  if (gid < out_n) {
    int c = s2 - s;
    float mean = sums[b] / (float)(c > 1 ? c : 1);
    out[gid] = fminf(fmaxf(mean, 0.f), 1.f);
  }
}

// ---------------------------------------------------------------------------
extern "C" void kernel_launch(void* const* d_in, const int* in_sizes, int n_in,
                              void* d_out, int out_size, void* d_ws,
                              size_t ws_size, hipStream_t stream) {
  const float* flux = (const float*)d_in[0];
  const float* lns  = (const float*)d_in[1];
  const float* lnv  = (const float*)d_in[2];
  const int*   ids  = (const int*)d_in[3];
  float* out = (float*)d_out;
  const int n = in_sizes[0];
  const int nbins = out_size + 2;

  // ws layout (floats): rot_w[1024] | gauss_w[1024] | comb_w[2048] |
  //                     bounds(int)[64] | sums[nbins]
  float* ws      = (float*)d_ws;
  float* rot_w   = ws;
  float* gauss_w = ws + 1024;
  float* comb_w  = ws + 2048;
  int*   bounds  = (int*)(ws + 4096);
  float* sums    = ws + 4160;

  hipMemsetAsync(sums, 0, (size_t)nbins * sizeof(float), stream);
  build_all<<<1, 1024, 0, stream>>>(lns, lnv, rot_w, gauss_w, comb_w, bounds);
  edge_fix<<<2, 256, 0, stream>>>(flux, rot_w, gauss_w, bounds, ids, sums, n);
  const int nblk = (n + OPB - 1) / OPB;
  conv_scatter<<<nblk, CB, 0, stream>>>(flux, comb_w, bounds, ids, sums, n);
  seg_mean<<<(out_size + 255) / 256, 256, 0, stream>>>(sums, ids, n, out,
                                                       out_size);
}

// Round 4
// 174.536 us; speedup vs baseline: 1.3195x; 1.3195x over previous
//
#include <hip/hip_runtime.h>
#include <hip/hip_bf16.h>

#define TAPS 901
#define CB 256
#define R 15
#define NK 240                  // fixed tap-window (16 groups of 15)
#define OPB (CB * R)            // 3840 outputs per block
#define TILE 4096               // staged window floats (>= 255*15+254+1), 16 KB

__device__ __forceinline__ float4 ld4(const float* p) {
  return *reinterpret_cast<const float4*>(p);
}

// ---------------------------------------------------------------------------
// Kernel 1: build rot/gauss kernels, combined kernel comb = conv(rot,gauss),
// and bounds. comb window trimmed to width NK by dropping smallest-|w| end
// taps (dropped mass ~1e-5). bounds = {clo4, flo, fhi, rlo, rhi, glo, ghi}
//   main conv: c[i] = sum_{t=clo4}^{clo4+NK-1} comb[t] * f[i + t - 900]
// ---------------------------------------------------------------------------
__global__ __launch_bounds__(1024) void build_all(
    const float* __restrict__ lns, const float* __restrict__ lnv,
    float* __restrict__ rot_w, float* __restrict__ gauss_w,
    float* __restrict__ comb_w, int* __restrict__ bounds) {
  __shared__ float rk[1024], gk[1024], red[1024];
  __shared__ float ck[2048];
  __shared__ int sb[8];  // {rlo,rhi,glo,ghi,clo,chi,-,-}
  const int t = threadIdx.x;
  if (t < 8) sb[t] = (t & 1) ? -1 : 4096;
  __syncthreads();

  const float sigma = 0.01f + expf(lns[0]);
  const float vsini = 0.9f + expf(lnv[0]);

  float rv = 0.f, gv = 0.f;
  if (t < TAPS) {
    float g = -4.5f + 0.01f * (float)t;
    float x = (299792.458f * g / 10500.0f) / vsini;
    float x2 = fminf(x * x, 1.0f);
    if (x2 < 1.0f) rv = 2.0f * sqrtf(1.0f - x2);  // 0.99999999f rounds to 1.0f
    gv = (1.0f / (sigma * sqrtf(2.0f * 3.1415926654f))) *
         expf(-0.5f * g * g / (sigma * sigma)) * 0.01f;
  }
  red[t] = rv;
  __syncthreads();
  for (int s = 512; s > 0; s >>= 1) {
    if (t < s) red[t] += red[t + s];
    __syncthreads();
  }
  const float rsum = red[0];

  const float rw = (t < TAPS) ? rv / rsum : 0.f;
  rk[t] = rw;
  gk[t] = gv;
  rot_w[t] = rw;
  gauss_w[t] = gv;
  if (t < TAPS) {
    if (rw != 0.f)          { atomicMin(&sb[0], t); atomicMax(&sb[1], t); }
    if (fabsf(gv) > 1e-10f) { atomicMin(&sb[2], t); atomicMax(&sb[3], t); }
  }
  __syncthreads();
  const int rlo = sb[0], rhi = sb[1], glo = sb[2], ghi = sb[3];

  // combined kernel comb[t] = sum_j rot[j]*gauss[t-j]  (t in [0,1800])
  for (int t2 = t; t2 < 2048; t2 += 1024) {
    float c = 0.f;
    if (t2 <= 1800) {
      int jmin = rlo > t2 - ghi ? rlo : t2 - ghi;
      int jmax = rhi < t2 - glo ? rhi : t2 - glo;
      for (int j = jmin; j <= jmax; ++j) c += rk[j] * gk[t2 - j];
    }
    ck[t2] = c;
    comb_w[t2] = c;
    if (t2 <= 1800 && fabsf(c) > 1e-12f) { atomicMin(&sb[4], t2); atomicMax(&sb[5], t2); }
  }
  __syncthreads();
  if (t == 0) {
    int clo = sb[4], chi = sb[5];
    if (chi < clo) { clo = 900; chi = 900; }
    // trim smallest-|w| end taps until aligned window width fits NK
    while (chi - (clo & ~3) + 1 > NK) {
      if (fabsf(ck[clo]) <= fabsf(ck[chi])) ++clo; else --chi;
    }
    int clo4 = clo & ~3;
    int flo = 450 - glo; if (flo < 0) flo = 0;
    int fhi = ghi - 450; if (fhi < 0) fhi = 0;
    bounds[0] = clo4; bounds[1] = flo; bounds[2] = fhi;
    bounds[3] = rlo;  bounds[4] = rhi; bounds[5] = glo; bounds[6] = ghi;
  }
}

// ---------------------------------------------------------------------------
// Kernel 2: exact two-stage conv for the edge pixels the combined form gets
// wrong (i < flo, i >= n-fhi), scattered into sums. 2 blocks (lo/hi edge).
// ---------------------------------------------------------------------------
__global__ __launch_bounds__(256) void edge_fix(
    const float* __restrict__ flux, const float* __restrict__ rot_w,
    const float* __restrict__ gauss_w, const int* __restrict__ bounds,
    const int* __restrict__ ids, float* __restrict__ sums, int n) {
  __shared__ float rbuf[928];
  const int tid = threadIdx.x;
  const int flo = bounds[1], fhi = bounds[2];
  const int rlo = bounds[3], rhi = bounds[4], glo = bounds[5], ghi = bounds[6];
  const int m = flo + fhi;  // r-values needed per edge (<= 901)

  if (blockIdx.x == 0) {
    for (int j = tid; j < m; j += 256) {
      float s = 0.f;
      int j0 = 450 - j > rlo ? 450 - j : rlo;  // f index >= 0
      for (int j2 = j0; j2 <= rhi; ++j2) s += rot_w[j2] * flux[j + j2 - 450];
      rbuf[j] = s;
    }
    __syncthreads();
    for (int i = tid; i < flo; i += 256) {
      float c = 0.f;
      int k0 = 450 - i > glo ? 450 - i : glo;  // r index >= 0
      for (int k = k0; k <= ghi; ++k) c += gauss_w[k] * rbuf[i + k - 450];
      atomicAdd(&sums[ids[i]], c);
    }
  } else {
    const int jbase = n - m;
    for (int jj = tid; jj < m; jj += 256) {
      int j = jbase + jj;
      float s = 0.f;
      int j2hi = n - 1 + 450 - j < rhi ? n - 1 + 450 - j : rhi;  // f index < n
      for (int j2 = rlo; j2 <= j2hi; ++j2) s += rot_w[j2] * flux[j + j2 - 450];
      rbuf[jj] = s;
    }
    __syncthreads();
    for (int ii = tid; ii < fhi; ii += 256) {
      int i = n - fhi + ii;
      float c = 0.f;
      int khi = n - 1 + 450 - i < ghi ? n - 1 + 450 - i : ghi;  // r index < n
      for (int k = glo; k <= khi; ++k) c += gauss_w[k] * rbuf[i + k - 450 - jbase];
      atomicAdd(&sums[ids[i]], c);
    }
  }
}

// ---------------------------------------------------------------------------
// Kernel 3: fused combined-conv + segment-sum scatter.
// R=15 outputs/thread: b32 sliding-window ring at lane stride 15 floats
// (gcd(15,32)=1 -> 2 lanes/bank -> conflict-free, m136). Weights are
// wave-uniform scalar loads from global (s_load path, off the LDS pipe).
// ---------------------------------------------------------------------------
__global__ __launch_bounds__(CB) void conv_scatter(
    const float* __restrict__ flux, const float* __restrict__ comb_w,
    const int* __restrict__ bounds, const int* __restrict__ ids,
    float* __restrict__ sums, int n) {
  __shared__ __align__(16) float lds[TILE];
  const int tid = threadIdx.x;
  const int clo4 = __builtin_amdgcn_readfirstlane(bounds[0]);
  const int flo  = __builtin_amdgcn_readfirstlane(bounds[1]);
  const int fhi  = __builtin_amdgcn_readfirstlane(bounds[2]);
  const int blockBase = blockIdx.x * OPB;
  const int start = blockBase - 900 + clo4;  // multiple of 4 -> float4-aligned

  // stage window: lds[j] = f_zeropad[start + j], j in [0, 4080)
  for (int j = tid * 4; j < OPB + NK; j += CB * 4) {
    int g = start + j;
    float4 v;
    if (g >= 0 && g + 3 < n) {
      v = ld4(flux + g);
    } else {
      v.x = (unsigned)g       < (unsigned)n ? flux[g]     : 0.f;
      v.y = (unsigned)(g + 1) < (unsigned)n ? flux[g + 1] : 0.f;
      v.z = (unsigned)(g + 2) < (unsigned)n ? flux[g + 2] : 0.f;
      v.w = (unsigned)(g + 3) < (unsigned)n ? flux[g + 3] : 0.f;
    }
    *reinterpret_cast<float4*>(&lds[j]) = v;
  }
  __syncthreads();

  const int idx0 = tid * R;
  float win[R];
#pragma unroll
  for (int r = 0; r < R; ++r) win[r] = lds[idx0 + r];
  float acc[R];
#pragma unroll
  for (int r = 0; r < R; ++r) acc[r] = 0.f;

  const float* wp = comb_w + clo4;  // uniform -> weight loads scalarize
#pragma unroll 2
  for (int g = 0; g < NK / R; ++g) {
    const int kk = g * R;
#pragma unroll
    for (int u = 0; u < R; ++u) {
      const float wk = wp[kk + u];
#pragma unroll
      for (int r = 0; r < R; ++r)
        acc[r] = fmaf(wk, win[(u + r) % R], acc[r]);
      win[u] = lds[idx0 + kk + u + R];  // refill oldest slot
    }
  }

  // run-merged scatter (sorted ids); skip edge pixels handled by edge_fix
  const int base = blockBase + idx0;
  const int loskip = flo - base;        // r < loskip invalid
  const int hicap = (n - fhi) - base;   // r >= hicap invalid
  int cur = -1; float run = 0.f;
#pragma unroll
  for (int r = 0; r < R; ++r) {
    if (r >= loskip && r < hicap) {
      int id = ids[base + r];
      if (id == cur) {
        run += acc[r];
      } else {
        if (cur >= 0) atomicAdd(&sums[cur], run);
        cur = id; run = acc[r];
      }
    }
  }
  if (cur >= 0) atomicAdd(&sums[cur], run);
}

// ---------------------------------------------------------------------------
// Kernel 4: per-bin mean; counts via binary search on sorted ids.
// ---------------------------------------------------------------------------
__global__ __launch_bounds__(256) void seg_mean(
    const float* __restrict__ sums, const int* __restrict__ ids, int n,
    float* __restrict__ out, int out_n) {
  const int gid = blockIdx.x * blockDim.x + threadIdx.x;
  const int b = (gid < out_n) ? gid + 1 : out_n;
  int lo = 0, hi = n;
  while (lo < hi) {
    int mid = (lo + hi) >> 1;
    if (ids[mid] < b) lo = mid + 1; else hi = mid;
  }
  const int s = lo;
  int s2 = __shfl_down(s, 1);
  const int lane = threadIdx.x & 63;
  if (lane == 63 || gid >= out_n - 1) {
    lo = s; hi = n;
    while (lo < hi) {
      int mid = (lo + hi) >> 1;
      if (ids[mid] < b + 1) lo = mid + 1; else hi = mid;
    }
    s2 = lo;
  }
  if (gid < out_n) {
    int c = s2 - s;
    float mean = sums[b] / (float)(c > 1 ? c : 1);
    out[gid] = fminf(fmaxf(mean, 0.f), 1.f);
  }
}

// ---------------------------------------------------------------------------
extern "C" void kernel_launch(void* const* d_in, const int* in_sizes, int n_in,
                              void* d_out, int out_size, void* d_ws,
                              size_t ws_size, hipStream_t stream) {
  const float* flux = (const float*)d_in[0];
  const float* lns  = (const float*)d_in[1];
  const float* lnv  = (const float*)d_in[2];
  const int*   ids  = (const int*)d_in[3];
  float* out = (float*)d_out;
  const int n = in_sizes[0];
  const int nbins = out_size + 2;

  // ws layout (floats): rot_w[1024] | gauss_w[1024] | comb_w[2048] |
  //                     bounds(int)[64] | sums[nbins]
  float* ws      = (float*)d_ws;
  float* rot_w   = ws;
  float* gauss_w = ws + 1024;
  float* comb_w  = ws + 2048;
  int*   bounds  = (int*)(ws + 4096);
  float* sums    = ws + 4160;

  hipMemsetAsync(sums, 0, (size_t)nbins * sizeof(float), stream);
  build_all<<<1, 1024, 0, stream>>>(lns, lnv, rot_w, gauss_w, comb_w, bounds);
  edge_fix<<<2, 256, 0, stream>>>(flux, rot_w, gauss_w, bounds, ids, sums, n);
  const int nblk = (n + OPB - 1) / OPB;
  conv_scatter<<<nblk, CB, 0, stream>>>(flux, comb_w, bounds, ids, sums, n);
  seg_mean<<<(out_size + 255) / 256, 256, 0, stream>>>(sums, ids, n, out,
                                                       out_size);
}

// Round 6
// 141.181 us; speedup vs baseline: 1.6312x; 1.2363x over previous
//
#include <hip/hip_runtime.h>
#include <hip/hip_bf16.h>

#define TAPS 901
#define CB 256
#define R 15
#define NGRP 16
#define NK (R * NGRP)           // 240 taps
#define OPB (CB * R)            // 3840 outputs per block
#define TILE 4112               // staged window floats (>= 255*15+14+240+pad)

__device__ __forceinline__ float4 ld4(const float* p) {
  return *reinterpret_cast<const float4*>(p);
}

// ---------------------------------------------------------------------------
// Kernel 1 (3 blocks): block 0 builds comb = conv(rot,gauss) trimmed to NK
// taps + bounds{clo4, flo, fhi}; blocks 1/2 recompute rot/gauss locally and
// do the exact two-stage conv for the lo/hi edge pixels (i<flo, i>=n-fhi)
// where the combined form differs from the reference's zero-padded two-pass.
// ---------------------------------------------------------------------------
__global__ __launch_bounds__(1024) void prep(
    const float* __restrict__ lns, const float* __restrict__ lnv,
    const float* __restrict__ flux, const int* __restrict__ ids,
    float* __restrict__ comb_w, int* __restrict__ bounds,
    float* __restrict__ sums, int n) {
  __shared__ float rk[1024], gk[1024], red[1024];
  __shared__ float ck[2048];            // block0: comb; blocks1/2: rbuf
  __shared__ int sb[8];                 // {rlo,rhi,glo,ghi,clo,chi,-,-}
  const int t = threadIdx.x;
  if (t < 8) sb[t] = (t & 1) ? -1 : 4096;
  __syncthreads();

  const float sigma = 0.01f + expf(lns[0]);
  const float vsini = 0.9f + expf(lnv[0]);

  float rv = 0.f, gv = 0.f;
  if (t < TAPS) {
    float g = -4.5f + 0.01f * (float)t;
    float x = (299792.458f * g / 10500.0f) / vsini;
    float x2 = fminf(x * x, 1.0f);
    if (x2 < 1.0f) rv = 2.0f * sqrtf(1.0f - x2);  // 0.99999999f rounds to 1.0f
    gv = (1.0f / (sigma * sqrtf(2.0f * 3.1415926654f))) *
         expf(-0.5f * g * g / (sigma * sigma)) * 0.01f;
  }
  red[t] = rv;
  __syncthreads();
  for (int s = 512; s > 0; s >>= 1) {
    if (t < s) red[t] += red[t + s];
    __syncthreads();
  }
  const float rsum = red[0];

  const float rw = (t < TAPS) ? rv / rsum : 0.f;
  rk[t] = rw;
  gk[t] = gv;
  if (t < TAPS) {
    if (rw != 0.f)          { atomicMin(&sb[0], t); atomicMax(&sb[1], t); }
    if (fabsf(gv) > 1e-10f) { atomicMin(&sb[2], t); atomicMax(&sb[3], t); }
  }
  __syncthreads();
  const int rlo = sb[0], rhi = sb[1], glo = sb[2], ghi = sb[3];
  int flo = 450 - glo; if (flo < 0) flo = 0;
  int fhi = ghi - 450; if (fhi < 0) fhi = 0;

  if (blockIdx.x == 0) {
    // combined kernel comb[t2] = sum_j rot[j]*gauss[t2-j], t2 in [0,1800]
    for (int t2 = t; t2 < 2048; t2 += 1024) {
      float c = 0.f;
      if (t2 <= 1800) {
        int jmin = rlo > t2 - ghi ? rlo : t2 - ghi;
        int jmax = rhi < t2 - glo ? rhi : t2 - glo;
        for (int j = jmin; j <= jmax; ++j) c += rk[j] * gk[t2 - j];
      }
      ck[t2] = c;
      comb_w[t2] = c;
      if (t2 <= 1800 && fabsf(c) > 1e-12f) { atomicMin(&sb[4], t2); atomicMax(&sb[5], t2); }
    }
    __syncthreads();
    if (t == 0) {
      int clo = sb[4], chi = sb[5];
      if (chi < clo) { clo = 900; chi = 900; }
      // trim smallest-|w| end taps until aligned window width fits NK
      while (chi - (clo & ~3) + 1 > NK) {
        if (fabsf(ck[clo]) <= fabsf(ck[chi])) ++clo; else --chi;
      }
      bounds[0] = clo & ~3; bounds[1] = flo; bounds[2] = fhi;
    }
  } else if (blockIdx.x == 1) {
    // lo edge: pixels i in [0, flo); r[j] for j in [0, m)
    const int m = flo + fhi;
    float* rbuf = ck;
    for (int j = t; j < m; j += 1024) {
      float s = 0.f;
      int j0 = 450 - j > rlo ? 450 - j : rlo;  // f index >= 0
      for (int j2 = j0; j2 <= rhi; ++j2) s += rk[j2] * flux[j + j2 - 450];
      rbuf[j] = s;
    }
    __syncthreads();
    for (int i = t; i < flo; i += 1024) {
      float c = 0.f;
      int k0 = 450 - i > glo ? 450 - i : glo;  // r index >= 0
      for (int k = k0; k <= ghi; ++k) c += gk[k] * rbuf[i + k - 450];
      atomicAdd(&sums[ids[i]], c);
    }
  } else {
    // hi edge: pixels i in [n-fhi, n); r[j] for j in [n-m, n)
    const int m = flo + fhi;
    float* rbuf = ck;
    const int jbase = n - m;
    for (int jj = t; jj < m; jj += 1024) {
      int j = jbase + jj;
      float s = 0.f;
      int j2hi = n - 1 + 450 - j < rhi ? n - 1 + 450 - j : rhi;  // f index < n
      for (int j2 = rlo; j2 <= j2hi; ++j2) s += rk[j2] * flux[j + j2 - 450];
      rbuf[jj] = s;
    }
    __syncthreads();
    for (int ii = t; ii < fhi; ii += 1024) {
      int i = n - fhi + ii;
      float c = 0.f;
      int khi = n - 1 + 450 - i < ghi ? n - 1 + 450 - i : ghi;  // r index < n
      for (int k = glo; k <= khi; ++k) c += gk[k] * rbuf[i + k - 450 - jbase];
      atomicAdd(&sums[ids[i]], c);
    }
  }
}

// ---------------------------------------------------------------------------
// Kernel 2: fused combined-conv + segment-sum scatter + bin-boundary scan.
// - window: stride-15 b32 ring (odd dword stride -> conflict-free, m136)
// - weights: LDS, 15+1-pad layout so each 15-tap group = 4 aligned float4
//   broadcast reads (no VMEM, single lgkmcnt domain)
// - epilogue: run-merged atomic scatter into sums + start[] boundary writes
//   (replaces 350k binary searches in the mean kernel)
// ---------------------------------------------------------------------------
__global__ __launch_bounds__(CB) void conv_scatter(
    const float* __restrict__ flux, const float* __restrict__ comb_w,
    const int* __restrict__ bounds, const int* __restrict__ ids,
    float* __restrict__ sums, int* __restrict__ bstart, int n, int nbins) {
  __shared__ __align__(16) float lds[TILE];
  __shared__ __align__(16) float wl[NGRP * 16];   // padded: [g*16+u], u<15
  const int tid = threadIdx.x;
  const int clo4 = __builtin_amdgcn_readfirstlane(bounds[0]);
  const int flo  = __builtin_amdgcn_readfirstlane(bounds[1]);
  const int fhi  = __builtin_amdgcn_readfirstlane(bounds[2]);
  const int blockBase = blockIdx.x * OPB;
  const int start = blockBase - 900 + clo4;  // multiple of 4 -> float4-aligned

  // stage window: lds[j] = f_zeropad[start + j]
  for (int j = tid * 4; j < OPB + NK; j += CB * 4) {
    int g = start + j;
    float4 v;
    if (g >= 0 && g + 3 < n) {
      v = ld4(flux + g);
    } else {
      v.x = (unsigned)g       < (unsigned)n ? flux[g]     : 0.f;
      v.y = (unsigned)(g + 1) < (unsigned)n ? flux[g + 1] : 0.f;
      v.z = (unsigned)(g + 2) < (unsigned)n ? flux[g + 2] : 0.f;
      v.w = (unsigned)(g + 3) < (unsigned)n ? flux[g + 3] : 0.f;
    }
    *reinterpret_cast<float4*>(&lds[j]) = v;
  }
  // weights, padded: slot = g*16+u <-> tap g*15+u (u<15); u==15 -> 0 pad
  {
    const int g = tid >> 4, u = tid & 15;
    wl[tid] = (u < 15) ? comb_w[clo4 + g * 15 + u] : 0.f;
  }
  __syncthreads();

  const int idx0 = tid * R;
  float win[R];
#pragma unroll
  for (int r = 0; r < R; ++r) win[r] = lds[idx0 + r];
  float acc[R];
#pragma unroll
  for (int r = 0; r < R; ++r) acc[r] = 0.f;

  const float4* wl4 = reinterpret_cast<const float4*>(wl);
#define TAP(u, wv)                                                     \
  {                                                                    \
    _Pragma("unroll") for (int r = 0; r < R; ++r)                      \
        acc[r] = fmaf(wv, win[((u) + r) % R], acc[r]);                 \
    win[u] = lds[idx0 + kk + (u) + R];                                 \
  }
#pragma unroll 2
  for (int g = 0; g < NGRP; ++g) {
    const int kk = g * R;
    const float4 q0 = wl4[g * 4 + 0];
    const float4 q1 = wl4[g * 4 + 1];
    const float4 q2 = wl4[g * 4 + 2];
    const float4 q3 = wl4[g * 4 + 3];
    TAP(0, q0.x)  TAP(1, q0.y)  TAP(2, q0.z)  TAP(3, q0.w)
    TAP(4, q1.x)  TAP(5, q1.y)  TAP(6, q1.z)  TAP(7, q1.w)
    TAP(8, q2.x)  TAP(9, q2.y)  TAP(10, q2.z) TAP(11, q2.w)
    TAP(12, q3.x) TAP(13, q3.y) TAP(14, q3.z)        // q3.w is pad
  }
#undef TAP

  // epilogue: run-merged scatter (skip edge pixels handled by prep) +
  // bin-start boundary writes for ALL owned pixels.
  const int base = blockBase + idx0;
  const int loskip = flo - base;        // r < loskip: edge-handled
  const int hicap = (n - fhi) - base;   // r >= hicap: edge-handled
  int prev = (base > 0) ? ((base < n) ? ids[base - 1] : 0) : -1;
  int cur = -1; float run = 0.f;
#pragma unroll
  for (int r = 0; r < R; ++r) {
    const int p = base + r;
    if (p < n) {
      const int id = ids[p];
      if (id != prev) {
        for (int b = prev + 1; b <= id; ++b) bstart[b] = p;
        prev = id;
      }
      if (r >= loskip && r < hicap) {
        if (id == cur) {
          run += acc[r];
        } else {
          if (cur >= 0) atomicAdd(&sums[cur], run);
          cur = id; run = acc[r];
        }
      }
    }
  }
  if (cur >= 0) atomicAdd(&sums[cur], run);
  // tail fill: thread owning pixel n-1 covers bins after the last id
  if (base < n && base + R > n - 1) {
    for (int b = prev + 1; b < nbins; ++b) bstart[b] = n;
  }
}

// ---------------------------------------------------------------------------
// Kernel 3: per-bin mean from precomputed bin starts (coalesced, no search).
// ---------------------------------------------------------------------------
__global__ __launch_bounds__(256) void seg_mean(
    const float* __restrict__ sums, const int* __restrict__ bstart,
    float* __restrict__ out, int out_n) {
  const int gid = blockIdx.x * blockDim.x + threadIdx.x;
  if (gid >= out_n) return;
  const int b = gid + 1;
  const int c = bstart[b + 1] - bstart[b];
  const float mean = sums[b] / (float)(c > 1 ? c : 1);
  out[gid] = fminf(fmaxf(mean, 0.f), 1.f);
}

// ---------------------------------------------------------------------------
extern "C" void kernel_launch(void* const* d_in, const int* in_sizes, int n_in,
                              void* d_out, int out_size, void* d_ws,
                              size_t ws_size, hipStream_t stream) {
  const float* flux = (const float*)d_in[0];
  const float* lns  = (const float*)d_in[1];
  const float* lnv  = (const float*)d_in[2];
  const int*   ids  = (const int*)d_in[3];
  float* out = (float*)d_out;
  const int n = in_sizes[0];
  const int nbins = out_size + 2;

  // ws layout (floats): comb_w[2048] | bounds(int)[64] | sums[nbins] |
  //                     bstart(int)[nbins+1]
  float* ws      = (float*)d_ws;
  float* comb_w  = ws;
  int*   bounds  = (int*)(ws + 2048);
  float* sums    = ws + 2112;
  int*   bstart  = (int*)(sums + nbins);

  hipMemsetAsync(sums, 0, (size_t)nbins * sizeof(float), stream);
  prep<<<3, 1024, 0, stream>>>(lns, lnv, flux, ids, comb_w, bounds, sums, n);
  const int nblk = (n + OPB - 1) / OPB;
  conv_scatter<<<nblk, CB, 0, stream>>>(flux, comb_w, bounds, ids, sums,
                                        bstart, n, nbins);
  seg_mean<<<(out_size + 255) / 256, 256, 0, stream>>>(sums, bstart, out,
                                                       out_size);
}